// Round 15
// baseline (99.474 us; speedup 1.0000x reference)
//
#include <hip/hip_runtime.h>
#include <hip/hip_bf16.h>

typedef __bf16 bf16_t;
typedef bf16_t bf16x8 __attribute__((ext_vector_type(8)));
typedef bf16_t bf16x4 __attribute__((ext_vector_type(4)));
typedef float f32x4 __attribute__((ext_vector_type(4)));

#define MFMA16(a, b, c) __builtin_amdgcn_mfma_f32_16x16x32_bf16(a, b, c, 0, 0, 0)

typedef __attribute__((address_space(3))) unsigned int lds_u32_t;
typedef __attribute__((address_space(1))) const unsigned int glb_u32_t;

__device__ __forceinline__ void gload16(const void* g, void* l) {
    __builtin_amdgcn_global_load_lds((glb_u32_t*)g, (lds_u32_t*)l, 16, 0, 0);
}

// swizzled LDS read for 128B-row tiles: byte-col ^= (row&7)<<4
__device__ __forceinline__ bf16x8 lds8(const bf16_t* base, int row, int cb) {
    return *reinterpret_cast<const bf16x8*>(
        reinterpret_cast<const char*>(base) + row * 128 + (cb ^ ((row & 7) << 4)));
}

// ---------------------------------------------------------------------------
// Merged pre-pass: blocks [0,2048): X fp32 -> bf16; blocks [2048,2240):
// W [k][n] fp32 -> Wt [mat][n][k] bf16 (K-matrix scaled log2(e)/8).
// ---------------------------------------------------------------------------
__global__ __launch_bounds__(256) void prep_kernel(
    const float* __restrict__ X,
    const float* __restrict__ Wq, const float* __restrict__ Wk,
    const float* __restrict__ Wv,
    bf16_t* __restrict__ Xb, bf16_t* __restrict__ Wt)
{
    __shared__ float T[64][65];
    if (blockIdx.x < 2048) {
        const size_t i = ((size_t)blockIdx.x * 256 + threadIdx.x) * 8;
        const float4 v0 = *reinterpret_cast<const float4*>(&X[i]);
        const float4 v1 = *reinterpret_cast<const float4*>(&X[i + 4]);
        bf16x8 o;
        o[0] = (bf16_t)v0.x; o[1] = (bf16_t)v0.y; o[2] = (bf16_t)v0.z; o[3] = (bf16_t)v0.w;
        o[4] = (bf16_t)v1.x; o[5] = (bf16_t)v1.y; o[6] = (bf16_t)v1.z; o[7] = (bf16_t)v1.w;
        *reinterpret_cast<bf16x8*>(&Xb[i]) = o;
        return;
    }
    const int idx = (int)blockIdx.x - 2048;        // 0..191
    const int mat = idx >> 6;
    const int rem = idx & 63;
    const int k0 = (rem >> 3) * 64, n0 = (rem & 7) * 64;
    const float* W = (mat == 0) ? Wq : (mat == 1 ? Wk : Wv);
    const int r = threadIdx.x >> 4, c4 = (threadIdx.x & 15) * 4;

    for (int rep = 0; rep < 4; ++rep) {
        const int row = r + rep * 16;
        const float4 v = *reinterpret_cast<const float4*>(&W[(size_t)(k0 + row) * 512 + n0 + c4]);
        T[row][c4 + 0] = v.x; T[row][c4 + 1] = v.y;
        T[row][c4 + 2] = v.z; T[row][c4 + 3] = v.w;
    }
    __syncthreads();
    const float scl = (mat == 1) ? 0.1803368801111204f : 1.0f;  // log2(e)/8
    for (int rep = 0; rep < 4; ++rep) {
        const int nrow = r + rep * 16;
        bf16x4 o;
        for (int e = 0; e < 4; ++e) o[e] = (bf16_t)(T[c4 + e][nrow] * scl);
        *reinterpret_cast<bf16x4*>(&Wt[(size_t)mat * 262144 + (size_t)(n0 + nrow) * 512 + k0 + c4]) = o;
    }
}

// ---------------------------------------------------------------------------
// bf16 projection GEMM, 128x128 tile, BK=64, 4 waves (each 64x64 out).
// grid (64, 12): mat = y>>2, n0 = (y&3)*128.
// mat 0 -> Qb row-major; 1 -> Kb row-major (K pre-scaled);
// mat 2 -> Vt [bh][mt(64)][d(64)][p(64)] with in-tile perm
//   p = (loc&32)|(((loc>>2)&3)<<3)|(((loc>>4)&1)<<2)|(loc&3), loc = m&63 --
//   written COALESCED via an LDS transpose (1KB contiguous per wave-pass).
// ---------------------------------------------------------------------------
__global__ __launch_bounds__(256, 2) void proj_bf16(
    const bf16_t* __restrict__ Xb, const bf16_t* __restrict__ Wt,
    bf16_t* __restrict__ Qb, bf16_t* __restrict__ Kb, bf16_t* __restrict__ Vt)
{
    __shared__ __align__(16) char smemP[65536];
    bf16_t* Ab0 = (bf16_t*)smemP;             // [2][128*64]
    bf16_t* Bb0 = (bf16_t*)(smemP + 32768);   // [2][128*64]

    const int tid = threadIdx.x;
    const int w = tid >> 6, l = tid & 63, g = l >> 4, lr = l & 15;
    const int m0 = blockIdx.x * 128;
    const int mat = blockIdx.y >> 2;
    const int n0 = (blockIdx.y & 3) * 128;
    const bf16_t* Wm = Wt + (size_t)mat * 262144;
    const int wm = (w >> 1) * 64, wn = (w & 1) * 64;

#define STAGE_P(buf, k0v)                                                   \
    do {                                                                    \
        for (int t = 0; t < 4; ++t) {                                       \
            const int rb = w * 32 + t * 8;                                  \
            const int row = rb + (l >> 3);                                  \
            const int cb = ((l & 7) << 4) ^ ((row & 7) << 4);               \
            gload16(&Xb[(size_t)(m0 + row) * 512 + (k0v) + (cb >> 1)],      \
                    Ab0 + (buf) * 8192 + rb * 64);                          \
            gload16(&Wm[(size_t)(n0 + row) * 512 + (k0v) + (cb >> 1)],      \
                    Bb0 + (buf) * 8192 + rb * 64);                          \
        }                                                                   \
    } while (0)

    f32x4 acc[4][4];
    const f32x4 z4 = {0.f, 0.f, 0.f, 0.f};
#pragma unroll
    for (int i = 0; i < 4; ++i)
#pragma unroll
        for (int j = 0; j < 4; ++j) acc[i][j] = z4;

    STAGE_P(0, 0);
    __syncthreads();

    for (int kk = 0; kk < 8; ++kk) {
        const int cur = kk & 1;
        if (kk + 1 < 8) STAGE_P(cur ^ 1, (kk + 1) * 64);

        bf16x8 a[4][2], bq[4][2];
#pragma unroll
        for (int fa = 0; fa < 4; ++fa)
#pragma unroll
            for (int dh = 0; dh < 2; ++dh) {
                a[fa][dh]  = lds8(Ab0 + cur * 8192, wm + fa * 16 + lr, dh * 64 + g * 16);
                bq[fa][dh] = lds8(Bb0 + cur * 8192, wn + fa * 16 + lr, dh * 64 + g * 16);
            }
        __builtin_amdgcn_s_setprio(1);
#pragma unroll
        for (int fa = 0; fa < 4; ++fa)
#pragma unroll
            for (int fb = 0; fb < 4; ++fb) {
                acc[fa][fb] = MFMA16(a[fa][0], bq[fb][0], acc[fa][fb]);
                acc[fa][fb] = MFMA16(a[fa][1], bq[fb][1], acc[fa][fb]);
            }
        __builtin_amdgcn_s_setprio(0);
        __syncthreads();
    }
#undef STAGE_P

    if (mat <= 1) {
        bf16_t* C = (mat == 0) ? Qb : Kb;
#pragma unroll
        for (int fa = 0; fa < 4; ++fa)
#pragma unroll
            for (int fb = 0; fb < 4; ++fb) {
#pragma unroll
                for (int j = 0; j < 4; ++j) {
                    const int m = m0 + wm + fa * 16 + g * 4 + j;
                    const int n = n0 + wn + fb * 16 + lr;
                    C[(size_t)m * 512 + n] = (bf16_t)acc[fa][fb][j];
                }
            }
        return;
    }

    // ---- mat == 2: LDS transpose, then coalesced Vt writes ----
    bf16_t* vt_lds = (bf16_t*)smemP;            // [128 n][132 m] bf16
#pragma unroll
    for (int fa = 0; fa < 4; ++fa)
#pragma unroll
        for (int fb = 0; fb < 4; ++fb) {
            const int ml = wm + fa * 16 + g * 4;        // j in low 2 bits
            const int loc = ml & 63;
            const int p = (loc & 32) | (((loc >> 2) & 3) << 3) |
                          (((loc >> 4) & 1) << 2) | (loc & 3);
            const int col = ((ml >> 6) << 6) + p;       // mt_local*64 + p
            const int nl = wn + fb * 16 + lr;
            bf16x4 v4;
#pragma unroll
            for (int j = 0; j < 4; ++j) v4[j] = (bf16_t)acc[fa][fb][j];
            *reinterpret_cast<bf16x4*>(&vt_lds[nl * 132 + col]) = v4;
        }
    __syncthreads();

    const int hh0 = n0 >> 6;
    const int b_ = m0 >> 12;
    const int mt0 = (m0 & 4095) >> 6;
#pragma unroll
    for (int pass = 0; pass < 8; ++pass) {
        const int unit = pass * 32 + w * 8 + (l >> 3);  // 0..255
        const int row = unit & 127;                     // n_local
        const int mt_half = unit >> 7;                  // 0/1
        const int d = row & 63, hh = hh0 + (row >> 6);
        const int bh_ = b_ * 8 + hh;
        const int mt = mt0 + mt_half;
        const bf16x8 v8 = *reinterpret_cast<const bf16x8*>(
            &vt_lds[row * 132 + mt_half * 64 + (l & 7) * 8]);
        *reinterpret_cast<bf16x8*>(
            &Vt[(size_t)bh_ * 262144 + (size_t)mt * 4096 + d * 64 + (l & 7) * 8]) = v8;
    }
}

// ---------------------------------------------------------------------------
// Legacy fp32-input projection (fallback for small ws). Writes NEW Vt layout.
// ---------------------------------------------------------------------------
__global__ __launch_bounds__(256) void proj_kernel(
    const float* __restrict__ X,
    const float* __restrict__ Wq, const float* __restrict__ Wk,
    const float* __restrict__ Wv,
    bf16_t* __restrict__ Qb, bf16_t* __restrict__ Kb, bf16_t* __restrict__ Vt)
{
    __shared__ bf16_t Ax[128][40];
    __shared__ bf16_t Wtl[64][40];

    const int mode = blockIdx.z;
    const float* W = (mode == 0) ? Wq : (mode == 1 ? Wk : Wv);
    bf16_t* C = (mode == 0) ? Qb : (mode == 1 ? Kb : Vt);

    const int tid = threadIdx.x;
    const int w = tid >> 6, l = tid & 63, g = l >> 4, lr = l & 15;
    const int m0 = blockIdx.x * 128, n0 = blockIdx.y * 64;

    f32x4 acc[2][4];
    const f32x4 z4 = {0.f, 0.f, 0.f, 0.f};
    for (int i = 0; i < 2; ++i)
        for (int j = 0; j < 4; ++j) acc[i][j] = z4;

    for (int k0 = 0; k0 < 512; k0 += 32) {
        {
            const int c4 = (tid & 7) * 4;
            for (int r = 0; r < 4; ++r) {
                const int row = (tid >> 3) + r * 32;
                const float4 v = *reinterpret_cast<const float4*>(
                    &X[(size_t)(m0 + row) * 512 + k0 + c4]);
                bf16x4 o;
                o[0] = (bf16_t)v.x; o[1] = (bf16_t)v.y;
                o[2] = (bf16_t)v.z; o[3] = (bf16_t)v.w;
                *reinterpret_cast<bf16x4*>(&Ax[row][c4]) = o;
            }
        }
        {
            const int c4 = (tid & 15) * 4;
            for (int r = 0; r < 2; ++r) {
                const int krow = (tid >> 4) + r * 16;
                const float4 v = *reinterpret_cast<const float4*>(
                    &W[(size_t)(k0 + krow) * 512 + n0 + c4]);
                Wtl[c4 + 0][krow] = (bf16_t)v.x;
                Wtl[c4 + 1][krow] = (bf16_t)v.y;
                Wtl[c4 + 2][krow] = (bf16_t)v.z;
                Wtl[c4 + 3][krow] = (bf16_t)v.w;
            }
        }
        __syncthreads();

        bf16x8 a[2], bq[4];
        for (int fr = 0; fr < 2; ++fr)
            a[fr] = *reinterpret_cast<const bf16x8*>(&Ax[w * 32 + fr * 16 + lr][g * 8]);
        for (int fn = 0; fn < 4; ++fn)
            bq[fn] = *reinterpret_cast<const bf16x8*>(&Wtl[fn * 16 + lr][g * 8]);
        for (int fr = 0; fr < 2; ++fr)
            for (int fn = 0; fn < 4; ++fn)
                acc[fr][fn] = MFMA16(a[fr], bq[fn], acc[fr][fn]);
        __syncthreads();
    }

    const float SCL = 0.125f * 1.44269504088896f;
    for (int fr = 0; fr < 2; ++fr)
        for (int fn = 0; fn < 4; ++fn)
            for (int j = 0; j < 4; ++j) {
                const int m = m0 + w * 32 + fr * 16 + g * 4 + j;
                const int n = n0 + fn * 16 + lr;
                float vf = acc[fr][fn][j];
                if (mode == 1) vf *= SCL;
                const bf16_t val = (bf16_t)vf;
                if (mode <= 1) {
                    C[(size_t)m * 512 + n] = val;
                } else {
                    const int b_ = m >> 12, mm = m & 4095;
                    const int hh = n >> 6, d = n & 63;
                    const int loc = mm & 63;
                    const int p = (loc & 32) | (((loc >> 2) & 3) << 3) |
                                  (((loc >> 4) & 1) << 2) | (loc & 3);
                    C[(size_t)(b_ * 8 + hh) * 262144 +
                      (size_t)(mm >> 6) * 4096 + d * 64 + p] = val;
                }
            }
}

// ---------------------------------------------------------------------------
// Attention core (r11/r14 structure): 512 blocks x 512 threads = 8 waves =
// 2 in-block m-half streams (mh) x 4 thin n-waves (u, 32 rows each).
// Per stream double-buffered 16 KB x 2 LDS (64 KB) -> 2 blocks/CU =
// 16 waves/CU = 4 waves/SIMD. Swapped QK^T keeps P in registers; no-max
// softmax (scale folded in Kb). r15 changes vs r14:
//  (1) ones-MFMA denominator deleted -> per-lane dl[] VALU sum in the exp
//      loop + end shfl_xor(16,32) + __shfl re-index (r12/r13-proven).
//  (2) tile split into two k-halves: QK(h0)->exp->pa[.][0]; then
//      {QK(h1) + PV(h0)} interleaved (16 independent MFMAs); exp; PV(h1).
// m-halves combined IN-BLOCK via LDS. XCD swizzle unchanged.
// ---------------------------------------------------------------------------
__global__ __launch_bounds__(512, 2) void attn_kernel(
    const bf16_t* __restrict__ Kb, const bf16_t* __restrict__ Qb,
    const bf16_t* __restrict__ Vt, float* __restrict__ Out)
{
    __shared__ __align__(16) char smem[65536];
    // stream mh, buffer b: Q tile at smem + mh*32768 + b*16384 (8 KB),
    //                      V tile at +8192 (8 KB)
    // post-loop alias: comb f32[128][65] @0 (33280 B), cden f32[128] @33280

    const int tid = threadIdx.x;
    const int w = tid >> 6, l = tid & 63, g = l >> 4, lr = l & 15;
    const int mh = w >> 2;          // m-half stream 0..1
    const int u = w & 3;            // n-sub wave 0..3 (32 rows each)

    const int id = ((int)blockIdx.x & 7) * 64 + ((int)blockIdx.x >> 3);
    const int bh = id >> 5, nb = id & 31;
    const int b = bh >> 3, hd = bh & 7;
    const int n0 = nb * 128;
    const int t0 = mh * 32;         // first m-tile of this stream (32 tiles)

    // K B-fragments in registers: wave covers n-rows n0 + u*32 .. +31
    bf16x8 ak[2][2];
#pragma unroll
    for (int fr = 0; fr < 2; ++fr)
#pragma unroll
        for (int dh = 0; dh < 2; ++dh)
            ak[fr][dh] = *reinterpret_cast<const bf16x8*>(
                &Kb[(size_t)(b * 4096 + n0 + u * 32 + fr * 16 + lr) * 512 +
                    hd * 64 + dh * 32 + g * 8]);

    // the 4 waves of a stream cooperatively stage their 64-row Q/V tile
#define STAGE(buf, m0v)                                                              \
    do {                                                                             \
        char* qls = smem + mh * 32768 + (buf) * 16384;                               \
        char* vls = qls + 8192;                                                      \
        for (int t = 0; t < 2; ++t) {                                                \
            const int row = u * 16 + t * 8 + (l >> 3);                               \
            const int cb = ((l & 7) << 4) ^ ((row & 7) << 4);                        \
            gload16(&Qb[(size_t)(b * 4096 + (m0v) + row) * 512 + hd * 64 + (cb >> 1)],\
                    qls + (u * 16 + t * 8) * 128);                                   \
            gload16(&Vt[(size_t)bh * 262144 + (size_t)((m0v) >> 6) * 4096 +          \
                        row * 64 + (cb >> 1)],                                       \
                    vls + (u * 16 + t * 8) * 128);                                   \
        }                                                                            \
    } while (0)

    f32x4 acc[2][4];
    float dl[2];
    const f32x4 z4 = {0.f, 0.f, 0.f, 0.f};
#pragma unroll
    for (int fr = 0; fr < 2; ++fr) {
        dl[fr] = 0.f;
#pragma unroll
        for (int j = 0; j < 4; ++j) acc[fr][j] = z4;
    }

    auto compute_tile = [&](int buf) {
        const bf16_t* qb = (const bf16_t*)(smem + mh * 32768 + buf * 16384);
        const bf16_t* vb = (const bf16_t*)(smem + mh * 32768 + buf * 16384 + 8192);
        bf16x8 pa[2][2];

        // ---- half 0: QK^T for m16 = 0,1 -> pa[.][0] ----
        {
            f32x4 s[2][2];
#pragma unroll
            for (int mm = 0; mm < 2; ++mm)
#pragma unroll
                for (int fr = 0; fr < 2; ++fr) s[mm][fr] = z4;
            __builtin_amdgcn_s_setprio(1);
#pragma unroll
            for (int mm = 0; mm < 2; ++mm) {
                const int r = mm * 16 + lr;
                const bf16x8 a0 = lds8(qb, r, g * 16);
                const bf16x8 a1 = lds8(qb, r, 64 + g * 16);
                s[mm][0] = MFMA16(a0, ak[0][0], s[mm][0]);
                s[mm][0] = MFMA16(a1, ak[0][1], s[mm][0]);
                s[mm][1] = MFMA16(a0, ak[1][0], s[mm][1]);
                s[mm][1] = MFMA16(a1, ak[1][1], s[mm][1]);
            }
            __builtin_amdgcn_s_setprio(0);
#pragma unroll
            for (int fr = 0; fr < 2; ++fr)
#pragma unroll
                for (int e = 0; e < 8; ++e) {
                    const float p = __builtin_amdgcn_exp2f(s[e >> 2][fr][e & 3]);
                    dl[fr] += p;
                    pa[fr][0][e] = (bf16_t)p;
                }
        }

        // ---- half 1 QK (m16 = 2,3) interleaved with PV half 0 ----
        {
            f32x4 s[2][2];
#pragma unroll
            for (int mm = 0; mm < 2; ++mm)
#pragma unroll
                for (int fr = 0; fr < 2; ++fr) s[mm][fr] = z4;
            __builtin_amdgcn_s_setprio(1);
#pragma unroll
            for (int mm = 0; mm < 2; ++mm) {
                const int r = (2 + mm) * 16 + lr;
                const bf16x8 a0 = lds8(qb, r, g * 16);
                const bf16x8 a1 = lds8(qb, r, 64 + g * 16);
                s[mm][0] = MFMA16(a0, ak[0][0], s[mm][0]);
                s[mm][0] = MFMA16(a1, ak[0][1], s[mm][0]);
                s[mm][1] = MFMA16(a0, ak[1][0], s[mm][1]);
                s[mm][1] = MFMA16(a1, ak[1][1], s[mm][1]);
            }
            // PV half 0 (independent of the QK above -> co-scheduled)
#pragma unroll
            for (int fd = 0; fd < 4; ++fd) {
                const bf16x8 v0 = lds8(vb, fd * 16 + lr, g * 16);
                acc[0][fd] = MFMA16(pa[0][0], v0, acc[0][fd]);
                acc[1][fd] = MFMA16(pa[1][0], v0, acc[1][fd]);
            }
            __builtin_amdgcn_s_setprio(0);
#pragma unroll
            for (int fr = 0; fr < 2; ++fr)
#pragma unroll
                for (int e = 0; e < 8; ++e) {
                    const float p = __builtin_amdgcn_exp2f(s[e >> 2][fr][e & 3]);
                    dl[fr] += p;
                    pa[fr][1][e] = (bf16_t)p;
                }
        }

        // ---- PV half 1 ----
        __builtin_amdgcn_s_setprio(1);
#pragma unroll
        for (int fd = 0; fd < 4; ++fd) {
            const bf16x8 v1 = lds8(vb, fd * 16 + lr, 64 + g * 16);
            acc[0][fd] = MFMA16(pa[0][1], v1, acc[0][fd]);
            acc[1][fd] = MFMA16(pa[1][1], v1, acc[1][fd]);
        }
        __builtin_amdgcn_s_setprio(0);
    };

    // ---- double-buffered loop, 32 tiles per stream ----
    STAGE(0, t0 * 64);
    __syncthreads();

    for (int it = 0; it < 32; ++it) {
        if (it + 1 < 32) STAGE((it + 1) & 1, (t0 + it + 1) * 64);
        compute_tile(it & 1);
        __syncthreads();
    }

    // ---- denominator: reduce over g-lanes (m axis), re-index col->row ----
    float denr[2][4];
#pragma unroll
    for (int fr = 0; fr < 2; ++fr) {
        float d = dl[fr];
        d += __shfl_xor(d, 16);
        d += __shfl_xor(d, 32);
#pragma unroll
        for (int j = 0; j < 4; ++j)
            denr[fr][j] = __shfl(d, g * 4 + j);   // den of n-row g*4+j (fr blk)
    }

    // ---- in-block combine of the 2 m-halves (LDS, 1 add-pass) ----
    float* comb = (float*)smem;             // [128][65] padded
    float* cden = (float*)(smem + 33280);   // [128]

    if (mh == 1) {
#pragma unroll
        for (int fr = 0; fr < 2; ++fr)
#pragma unroll
            for (int fd = 0; fd < 4; ++fd)
#pragma unroll
                for (int j = 0; j < 4; ++j)
                    comb[(u * 32 + fr * 16 + g * 4 + j) * 65 + fd * 16 + lr] =
                        acc[fr][fd][j];
        if (lr == 0) {
#pragma unroll
            for (int fr = 0; fr < 2; ++fr)
#pragma unroll
                for (int j = 0; j < 4; ++j)
                    cden[u * 32 + fr * 16 + g * 4 + j] = denr[fr][j];
        }
    }
    __syncthreads();
    if (mh == 0) {
        float linv[2][4];
#pragma unroll
        for (int fr = 0; fr < 2; ++fr)
#pragma unroll
            for (int j = 0; j < 4; ++j) {
                const int nl = u * 32 + fr * 16 + g * 4 + j;
                linv[fr][j] = 1.0f / (denr[fr][j] + cden[nl]);
            }
#pragma unroll
        for (int fr = 0; fr < 2; ++fr)
#pragma unroll
            for (int fd = 0; fd < 4; ++fd)
#pragma unroll
                for (int j = 0; j < 4; ++j) {
                    const int nl = u * 32 + fr * 16 + g * 4 + j;
                    const int d = fd * 16 + lr;
                    Out[((size_t)(b * 4096 + n0 + nl)) * 512 + hd * 64 + d] =
                        (acc[fr][fd][j] + comb[nl * 65 + d]) * linv[fr][j];
                }
    }
#undef STAGE
}

extern "C" void kernel_launch(void* const* d_in, const int* in_sizes, int n_in,
                              void* d_out, int out_size, void* d_ws, size_t ws_size,
                              hipStream_t stream)
{
    const float* x  = (const float*)d_in[0];
    const float* Wk = (const float*)d_in[1];
    const float* Wq = (const float*)d_in[2];
    const float* Wv = (const float*)d_in[3];
    float* out = (float*)d_out;

    char* ws = (char*)d_ws;
    bf16_t* Kb = (bf16_t*)ws;                 // [0, 8 MB)
    bf16_t* Qb = Kb + (size_t)4194304;        // [8, 16 MB)
    bf16_t* Vt = Qb + (size_t)4194304;        // [16, 24 MB)
    bf16_t* Xb = (bf16_t*)(ws + 25165824);    // [24, 32 MB)
    bf16_t* Wt = Xb + (size_t)4194304;        // [32, 33.5 MB)

    const size_t NEED_PRE = 35127296;         // through Wt
    const bool has_pre = ws_size >= NEED_PRE;

    if (has_pre) {
        hipLaunchKernelGGL(prep_kernel, dim3(2240), dim3(256), 0, stream,
                           x, Wq, Wk, Wv, Xb, Wt);
        hipLaunchKernelGGL(proj_bf16, dim3(64, 12), dim3(256), 0, stream,
                           Xb, Wt, Qb, Kb, Vt);
    } else {
        hipLaunchKernelGGL(proj_kernel, dim3(64, 8, 3), dim3(256), 0, stream,
                           x, Wq, Wk, Wv, Qb, Kb, Vt);
    }

    hipLaunchKernelGGL(attn_kernel, dim3(512), dim3(512), 0, stream,
                       Kb, Qb, Vt, out);
}

// Round 16
// 90.193 us; speedup vs baseline: 1.1029x; 1.1029x over previous
//
#include <hip/hip_runtime.h>
#include <hip/hip_bf16.h>

typedef __bf16 bf16_t;
typedef bf16_t bf16x8 __attribute__((ext_vector_type(8)));
typedef bf16_t bf16x4 __attribute__((ext_vector_type(4)));
typedef float f32x4 __attribute__((ext_vector_type(4)));

#define MFMA16(a, b, c) __builtin_amdgcn_mfma_f32_16x16x32_bf16(a, b, c, 0, 0, 0)

typedef __attribute__((address_space(3))) unsigned int lds_u32_t;
typedef __attribute__((address_space(1))) const unsigned int glb_u32_t;

__device__ __forceinline__ void gload16(const void* g, void* l) {
    __builtin_amdgcn_global_load_lds((glb_u32_t*)g, (lds_u32_t*)l, 16, 0, 0);
}

// swizzled LDS read for 128B-row tiles: byte-col ^= (row&7)<<4
__device__ __forceinline__ bf16x8 lds8(const bf16_t* base, int row, int cb) {
    return *reinterpret_cast<const bf16x8*>(
        reinterpret_cast<const char*>(base) + row * 128 + (cb ^ ((row & 7) << 4)));
}

// ---------------------------------------------------------------------------
// Merged pre-pass: blocks [0,2048): X fp32 -> bf16; blocks [2048,2240):
// W [k][n] fp32 -> Wt [mat][n][k] bf16 (K-matrix scaled log2(e)/8).
// ---------------------------------------------------------------------------
__global__ __launch_bounds__(256) void prep_kernel(
    const float* __restrict__ X,
    const float* __restrict__ Wq, const float* __restrict__ Wk,
    const float* __restrict__ Wv,
    bf16_t* __restrict__ Xb, bf16_t* __restrict__ Wt)
{
    __shared__ float T[64][65];
    if (blockIdx.x < 2048) {
        const size_t i = ((size_t)blockIdx.x * 256 + threadIdx.x) * 8;
        const float4 v0 = *reinterpret_cast<const float4*>(&X[i]);
        const float4 v1 = *reinterpret_cast<const float4*>(&X[i + 4]);
        bf16x8 o;
        o[0] = (bf16_t)v0.x; o[1] = (bf16_t)v0.y; o[2] = (bf16_t)v0.z; o[3] = (bf16_t)v0.w;
        o[4] = (bf16_t)v1.x; o[5] = (bf16_t)v1.y; o[6] = (bf16_t)v1.z; o[7] = (bf16_t)v1.w;
        *reinterpret_cast<bf16x8*>(&Xb[i]) = o;
        return;
    }
    const int idx = (int)blockIdx.x - 2048;        // 0..191
    const int mat = idx >> 6;
    const int rem = idx & 63;
    const int k0 = (rem >> 3) * 64, n0 = (rem & 7) * 64;
    const float* W = (mat == 0) ? Wq : (mat == 1 ? Wk : Wv);
    const int r = threadIdx.x >> 4, c4 = (threadIdx.x & 15) * 4;

    for (int rep = 0; rep < 4; ++rep) {
        const int row = r + rep * 16;
        const float4 v = *reinterpret_cast<const float4*>(&W[(size_t)(k0 + row) * 512 + n0 + c4]);
        T[row][c4 + 0] = v.x; T[row][c4 + 1] = v.y;
        T[row][c4 + 2] = v.z; T[row][c4 + 3] = v.w;
    }
    __syncthreads();
    const float scl = (mat == 1) ? 0.1803368801111204f : 1.0f;  // log2(e)/8
    for (int rep = 0; rep < 4; ++rep) {
        const int nrow = r + rep * 16;
        bf16x4 o;
        for (int e = 0; e < 4; ++e) o[e] = (bf16_t)(T[c4 + e][nrow] * scl);
        *reinterpret_cast<bf16x4*>(&Wt[(size_t)mat * 262144 + (size_t)(n0 + nrow) * 512 + k0 + c4]) = o;
    }
}

// ---------------------------------------------------------------------------
// bf16 projection GEMM, 128x128 tile, BK=64, 4 waves (each 64x64 out).
// grid (64, 12): mat = y>>2, n0 = (y&3)*128.
// mat 0 -> Qb row-major; 1 -> Kb row-major (K pre-scaled);
// mat 2 -> Vt [bh][mt(64)][d(64)][p(64)] with in-tile perm
//   p = (loc&32)|(((loc>>2)&3)<<3)|(((loc>>4)&1)<<2)|(loc&3), loc = m&63 --
//   written COALESCED via an LDS transpose (1KB contiguous per wave-pass).
// ---------------------------------------------------------------------------
__global__ __launch_bounds__(256, 2) void proj_bf16(
    const bf16_t* __restrict__ Xb, const bf16_t* __restrict__ Wt,
    bf16_t* __restrict__ Qb, bf16_t* __restrict__ Kb, bf16_t* __restrict__ Vt)
{
    __shared__ __align__(16) char smemP[65536];
    bf16_t* Ab0 = (bf16_t*)smemP;             // [2][128*64]
    bf16_t* Bb0 = (bf16_t*)(smemP + 32768);   // [2][128*64]

    const int tid = threadIdx.x;
    const int w = tid >> 6, l = tid & 63, g = l >> 4, lr = l & 15;
    const int m0 = blockIdx.x * 128;
    const int mat = blockIdx.y >> 2;
    const int n0 = (blockIdx.y & 3) * 128;
    const bf16_t* Wm = Wt + (size_t)mat * 262144;
    const int wm = (w >> 1) * 64, wn = (w & 1) * 64;

#define STAGE_P(buf, k0v)                                                   \
    do {                                                                    \
        for (int t = 0; t < 4; ++t) {                                       \
            const int rb = w * 32 + t * 8;                                  \
            const int row = rb + (l >> 3);                                  \
            const int cb = ((l & 7) << 4) ^ ((row & 7) << 4);               \
            gload16(&Xb[(size_t)(m0 + row) * 512 + (k0v) + (cb >> 1)],      \
                    Ab0 + (buf) * 8192 + rb * 64);                          \
            gload16(&Wm[(size_t)(n0 + row) * 512 + (k0v) + (cb >> 1)],      \
                    Bb0 + (buf) * 8192 + rb * 64);                          \
        }                                                                   \
    } while (0)

    f32x4 acc[4][4];
    const f32x4 z4 = {0.f, 0.f, 0.f, 0.f};
#pragma unroll
    for (int i = 0; i < 4; ++i)
#pragma unroll
        for (int j = 0; j < 4; ++j) acc[i][j] = z4;

    STAGE_P(0, 0);
    __syncthreads();

    for (int kk = 0; kk < 8; ++kk) {
        const int cur = kk & 1;
        if (kk + 1 < 8) STAGE_P(cur ^ 1, (kk + 1) * 64);

        bf16x8 a[4][2], bq[4][2];
#pragma unroll
        for (int fa = 0; fa < 4; ++fa)
#pragma unroll
            for (int dh = 0; dh < 2; ++dh) {
                a[fa][dh]  = lds8(Ab0 + cur * 8192, wm + fa * 16 + lr, dh * 64 + g * 16);
                bq[fa][dh] = lds8(Bb0 + cur * 8192, wn + fa * 16 + lr, dh * 64 + g * 16);
            }
        __builtin_amdgcn_s_setprio(1);
#pragma unroll
        for (int fa = 0; fa < 4; ++fa)
#pragma unroll
            for (int fb = 0; fb < 4; ++fb) {
                acc[fa][fb] = MFMA16(a[fa][0], bq[fb][0], acc[fa][fb]);
                acc[fa][fb] = MFMA16(a[fa][1], bq[fb][1], acc[fa][fb]);
            }
        __builtin_amdgcn_s_setprio(0);
        __syncthreads();
    }
#undef STAGE_P

    if (mat <= 1) {
        bf16_t* C = (mat == 0) ? Qb : Kb;
#pragma unroll
        for (int fa = 0; fa < 4; ++fa)
#pragma unroll
            for (int fb = 0; fb < 4; ++fb) {
#pragma unroll
                for (int j = 0; j < 4; ++j) {
                    const int m = m0 + wm + fa * 16 + g * 4 + j;
                    const int n = n0 + wn + fb * 16 + lr;
                    C[(size_t)m * 512 + n] = (bf16_t)acc[fa][fb][j];
                }
            }
        return;
    }

    // ---- mat == 2: LDS transpose, then coalesced Vt writes ----
    bf16_t* vt_lds = (bf16_t*)smemP;            // [128 n][132 m] bf16
#pragma unroll
    for (int fa = 0; fa < 4; ++fa)
#pragma unroll
        for (int fb = 0; fb < 4; ++fb) {
            const int ml = wm + fa * 16 + g * 4;        // j in low 2 bits
            const int loc = ml & 63;
            const int p = (loc & 32) | (((loc >> 2) & 3) << 3) |
                          (((loc >> 4) & 1) << 2) | (loc & 3);
            const int col = ((ml >> 6) << 6) + p;       // mt_local*64 + p
            const int nl = wn + fb * 16 + lr;
            bf16x4 v4;
#pragma unroll
            for (int j = 0; j < 4; ++j) v4[j] = (bf16_t)acc[fa][fb][j];
            *reinterpret_cast<bf16x4*>(&vt_lds[nl * 132 + col]) = v4;
        }
    __syncthreads();

    const int hh0 = n0 >> 6;
    const int b_ = m0 >> 12;
    const int mt0 = (m0 & 4095) >> 6;
#pragma unroll
    for (int pass = 0; pass < 8; ++pass) {
        const int unit = pass * 32 + w * 8 + (l >> 3);  // 0..255
        const int row = unit & 127;                     // n_local
        const int mt_half = unit >> 7;                  // 0/1
        const int d = row & 63, hh = hh0 + (row >> 6);
        const int bh_ = b_ * 8 + hh;
        const int mt = mt0 + mt_half;
        const bf16x8 v8 = *reinterpret_cast<const bf16x8*>(
            &vt_lds[row * 132 + mt_half * 64 + (l & 7) * 8]);
        *reinterpret_cast<bf16x8*>(
            &Vt[(size_t)bh_ * 262144 + (size_t)mt * 4096 + d * 64 + (l & 7) * 8]) = v8;
    }
}

// ---------------------------------------------------------------------------
// Legacy fp32-input projection (fallback for small ws). Writes NEW Vt layout.
// ---------------------------------------------------------------------------
__global__ __launch_bounds__(256) void proj_kernel(
    const float* __restrict__ X,
    const float* __restrict__ Wq, const float* __restrict__ Wk,
    const float* __restrict__ Wv,
    bf16_t* __restrict__ Qb, bf16_t* __restrict__ Kb, bf16_t* __restrict__ Vt)
{
    __shared__ bf16_t Ax[128][40];
    __shared__ bf16_t Wtl[64][40];

    const int mode = blockIdx.z;
    const float* W = (mode == 0) ? Wq : (mode == 1 ? Wk : Wv);
    bf16_t* C = (mode == 0) ? Qb : (mode == 1 ? Kb : Vt);

    const int tid = threadIdx.x;
    const int w = tid >> 6, l = tid & 63, g = l >> 4, lr = l & 15;
    const int m0 = blockIdx.x * 128, n0 = blockIdx.y * 64;

    f32x4 acc[2][4];
    const f32x4 z4 = {0.f, 0.f, 0.f, 0.f};
    for (int i = 0; i < 2; ++i)
        for (int j = 0; j < 4; ++j) acc[i][j] = z4;

    for (int k0 = 0; k0 < 512; k0 += 32) {
        {
            const int c4 = (tid & 7) * 4;
            for (int r = 0; r < 4; ++r) {
                const int row = (tid >> 3) + r * 32;
                const float4 v = *reinterpret_cast<const float4*>(
                    &X[(size_t)(m0 + row) * 512 + k0 + c4]);
                bf16x4 o;
                o[0] = (bf16_t)v.x; o[1] = (bf16_t)v.y;
                o[2] = (bf16_t)v.z; o[3] = (bf16_t)v.w;
                *reinterpret_cast<bf16x4*>(&Ax[row][c4]) = o;
            }
        }
        {
            const int c4 = (tid & 15) * 4;
            for (int r = 0; r < 2; ++r) {
                const int krow = (tid >> 4) + r * 16;
                const float4 v = *reinterpret_cast<const float4*>(
                    &W[(size_t)(k0 + krow) * 512 + n0 + c4]);
                Wtl[c4 + 0][krow] = (bf16_t)v.x;
                Wtl[c4 + 1][krow] = (bf16_t)v.y;
                Wtl[c4 + 2][krow] = (bf16_t)v.z;
                Wtl[c4 + 3][krow] = (bf16_t)v.w;
            }
        }
        __syncthreads();

        bf16x8 a[2], bq[4];
        for (int fr = 0; fr < 2; ++fr)
            a[fr] = *reinterpret_cast<const bf16x8*>(&Ax[w * 32 + fr * 16 + lr][g * 8]);
        for (int fn = 0; fn < 4; ++fn)
            bq[fn] = *reinterpret_cast<const bf16x8*>(&Wtl[fn * 16 + lr][g * 8]);
        for (int fr = 0; fr < 2; ++fr)
            for (int fn = 0; fn < 4; ++fn)
                acc[fr][fn] = MFMA16(a[fr], bq[fn], acc[fr][fn]);
        __syncthreads();
    }

    const float SCL = 0.125f * 1.44269504088896f;
    for (int fr = 0; fr < 2; ++fr)
        for (int fn = 0; fn < 4; ++fn)
            for (int j = 0; j < 4; ++j) {
                const int m = m0 + w * 32 + fr * 16 + g * 4 + j;
                const int n = n0 + fn * 16 + lr;
                float vf = acc[fr][fn][j];
                if (mode == 1) vf *= SCL;
                const bf16_t val = (bf16_t)vf;
                if (mode <= 1) {
                    C[(size_t)m * 512 + n] = val;
                } else {
                    const int b_ = m >> 12, mm = m & 4095;
                    const int hh = n >> 6, d = n & 63;
                    const int loc = mm & 63;
                    const int p = (loc & 32) | (((loc >> 2) & 3) << 3) |
                                  (((loc >> 4) & 1) << 2) | (loc & 3);
                    C[(size_t)(b_ * 8 + hh) * 262144 +
                      (size_t)(mm >> 6) * 4096 + d * 64 + p] = val;
                }
            }
}

// ---------------------------------------------------------------------------
// Attention core (r11/r14-proven, 73.3us): 512 blocks x 512 threads = 8
// waves = 2 in-block m-half streams (mh) x 4 thin n-waves (u, 32 rows each;
// 128 n-rows/block). Per stream: private double-buffered 16 KB x 2 LDS
// (64 KB total) -> 2 blocks/CU = 16 waves/CU = 4 waves/SIMD. Swapped QK^T
// keeps P in registers, no-max softmax (scale folded in Kb), denominator
// via ones-MFMA, m-halves combined IN-BLOCK via LDS. XCD swizzle: all 32
// nb of a bh per XCD. Vt layout [bh][mt][d][p] (coalesced proj writes).
// r15's interleave/VALU-denominator experiment REGRESSED (MfmaUtil 47->32:
// LDS reads inside the MFMA cluster added lgkmcnt fences) -- reverted.
// ---------------------------------------------------------------------------
__global__ __launch_bounds__(512, 2) void attn_kernel(
    const bf16_t* __restrict__ Kb, const bf16_t* __restrict__ Qb,
    const bf16_t* __restrict__ Vt, float* __restrict__ Out)
{
    __shared__ __align__(16) char smem[65536];
    // stream mh, buffer b: Q tile at smem + mh*32768 + b*16384 (8 KB),
    //                      V tile at +8192 (8 KB)
    // post-loop alias: comb f32[128][65] @0 (33280 B), cden f32[128] @33280

    const int tid = threadIdx.x;
    const int w = tid >> 6, l = tid & 63, g = l >> 4, lr = l & 15;
    const int mh = w >> 2;          // m-half stream 0..1
    const int u = w & 3;            // n-sub wave 0..3 (32 rows each)

    const int id = ((int)blockIdx.x & 7) * 64 + ((int)blockIdx.x >> 3);
    const int bh = id >> 5, nb = id & 31;
    const int b = bh >> 3, hd = bh & 7;
    const int n0 = nb * 128;
    const int t0 = mh * 32;         // first m-tile of this stream (32 tiles)

    // K B-fragments in registers: wave covers n-rows n0 + u*32 .. +31
    bf16x8 ak[2][2];
#pragma unroll
    for (int fr = 0; fr < 2; ++fr)
#pragma unroll
        for (int dh = 0; dh < 2; ++dh)
            ak[fr][dh] = *reinterpret_cast<const bf16x8*>(
                &Kb[(size_t)(b * 4096 + n0 + u * 32 + fr * 16 + lr) * 512 +
                    hd * 64 + dh * 32 + g * 8]);

    bf16x8 ones;
#pragma unroll
    for (int i = 0; i < 8; ++i) ones[i] = (bf16_t)1.0f;

    // the 4 waves of a stream cooperatively stage their 64-row Q/V tile
#define STAGE(buf, m0v)                                                              \
    do {                                                                             \
        char* qls = smem + mh * 32768 + (buf) * 16384;                               \
        char* vls = qls + 8192;                                                      \
        for (int t = 0; t < 2; ++t) {                                                \
            const int row = u * 16 + t * 8 + (l >> 3);                               \
            const int cb = ((l & 7) << 4) ^ ((row & 7) << 4);                        \
            gload16(&Qb[(size_t)(b * 4096 + (m0v) + row) * 512 + hd * 64 + (cb >> 1)],\
                    qls + (u * 16 + t * 8) * 128);                                   \
            gload16(&Vt[(size_t)bh * 262144 + (size_t)((m0v) >> 6) * 4096 +          \
                        row * 64 + (cb >> 1)],                                       \
                    vls + (u * 16 + t * 8) * 128);                                   \
        }                                                                            \
    } while (0)

    f32x4 acc[2][4];
    f32x4 dacc[2];
    const f32x4 z4 = {0.f, 0.f, 0.f, 0.f};
#pragma unroll
    for (int fr = 0; fr < 2; ++fr) {
        dacc[fr] = z4;
#pragma unroll
        for (int j = 0; j < 4; ++j) acc[fr][j] = z4;
    }

    auto compute_tile = [&](int buf) {
        const bf16_t* qb = (const bf16_t*)(smem + mh * 32768 + buf * 16384);
        const bf16_t* vb = (const bf16_t*)(smem + mh * 32768 + buf * 16384 + 8192);

        // ---- QK^T swapped: lane holds P[m = m16*16 + g*4 + j][n = lr] ----
        f32x4 s[4][2];
#pragma unroll
        for (int m16 = 0; m16 < 4; ++m16)
#pragma unroll
            for (int fr = 0; fr < 2; ++fr) s[m16][fr] = z4;

        __builtin_amdgcn_s_setprio(1);
#pragma unroll
        for (int m16 = 0; m16 < 4; ++m16) {
            const int r = m16 * 16 + lr;
            const bf16x8 a0 = lds8(qb, r, g * 16);
            const bf16x8 a1 = lds8(qb, r, 64 + g * 16);
            s[m16][0] = MFMA16(a0, ak[0][0], s[m16][0]);
            s[m16][0] = MFMA16(a1, ak[0][1], s[m16][0]);
            s[m16][1] = MFMA16(a0, ak[1][0], s[m16][1]);
            s[m16][1] = MFMA16(a1, ak[1][1], s[m16][1]);
        }
        __builtin_amdgcn_s_setprio(0);

        // ---- P = exp2(S) packed directly into PV A-fragments (no LDS) ----
        bf16x8 pa[2][2];
#pragma unroll
        for (int fr = 0; fr < 2; ++fr)
#pragma unroll
            for (int c = 0; c < 2; ++c)
#pragma unroll
                for (int e = 0; e < 8; ++e)
                    pa[fr][c][e] = (bf16_t)__builtin_amdgcn_exp2f(
                        s[c * 2 + (e >> 2)][fr][e & 3]);

        // ---- denominator (ones-MFMA) + PV ----
        __builtin_amdgcn_s_setprio(1);
        dacc[0] = MFMA16(pa[0][0], ones, dacc[0]);
        dacc[0] = MFMA16(pa[0][1], ones, dacc[0]);
        dacc[1] = MFMA16(pa[1][0], ones, dacc[1]);
        dacc[1] = MFMA16(pa[1][1], ones, dacc[1]);
#pragma unroll
        for (int fd = 0; fd < 4; ++fd) {
            const bf16x8 vb0 = lds8(vb, fd * 16 + lr, g * 16);
            const bf16x8 vb1 = lds8(vb, fd * 16 + lr, 64 + g * 16);
            acc[0][fd] = MFMA16(pa[0][0], vb0, acc[0][fd]);
            acc[0][fd] = MFMA16(pa[0][1], vb1, acc[0][fd]);
            acc[1][fd] = MFMA16(pa[1][0], vb0, acc[1][fd]);
            acc[1][fd] = MFMA16(pa[1][1], vb1, acc[1][fd]);
        }
        __builtin_amdgcn_s_setprio(0);
    };

    // ---- double-buffered loop, 32 tiles per stream ----
    STAGE(0, t0 * 64);
    __syncthreads();

    for (int it = 0; it < 32; ++it) {
        if (it + 1 < 32) STAGE((it + 1) & 1, (t0 + it + 1) * 64);
        compute_tile(it & 1);
        __syncthreads();
    }

    // ---- in-block combine of the 2 m-halves (LDS, 1 add-pass) ----
    float* comb = (float*)smem;             // [128][65] padded
    float* cden = (float*)(smem + 33280);   // [128]

    if (mh == 1) {
#pragma unroll
        for (int fr = 0; fr < 2; ++fr)
#pragma unroll
            for (int fd = 0; fd < 4; ++fd)
#pragma unroll
                for (int j = 0; j < 4; ++j)
                    comb[(u * 32 + fr * 16 + g * 4 + j) * 65 + fd * 16 + lr] =
                        acc[fr][fd][j];
        if (lr == 0) {
#pragma unroll
            for (int fr = 0; fr < 2; ++fr)
#pragma unroll
                for (int j = 0; j < 4; ++j)
                    cden[u * 32 + fr * 16 + g * 4 + j] = dacc[fr][j];
        }
    }
    __syncthreads();
    if (mh == 0) {
        float linv[2][4];
#pragma unroll
        for (int fr = 0; fr < 2; ++fr)
#pragma unroll
            for (int j = 0; j < 4; ++j) {
                const int nl = u * 32 + fr * 16 + g * 4 + j;
                linv[fr][j] = 1.0f / (dacc[fr][j] + cden[nl]);
            }
#pragma unroll
        for (int fr = 0; fr < 2; ++fr)
#pragma unroll
            for (int fd = 0; fd < 4; ++fd)
#pragma unroll
                for (int j = 0; j < 4; ++j) {
                    const int nl = u * 32 + fr * 16 + g * 4 + j;
                    const int d = fd * 16 + lr;
                    Out[((size_t)(b * 4096 + n0 + nl)) * 512 + hd * 64 + d] =
                        (acc[fr][fd][j] + comb[nl * 65 + d]) * linv[fr][j];
                }
    }
#undef STAGE
}

extern "C" void kernel_launch(void* const* d_in, const int* in_sizes, int n_in,
                              void* d_out, int out_size, void* d_ws, size_t ws_size,
                              hipStream_t stream)
{
    const float* x  = (const float*)d_in[0];
    const float* Wk = (const float*)d_in[1];
    const float* Wq = (const float*)d_in[2];
    const float* Wv = (const float*)d_in[3];
    float* out = (float*)d_out;

    char* ws = (char*)d_ws;
    bf16_t* Kb = (bf16_t*)ws;                 // [0, 8 MB)
    bf16_t* Qb = Kb + (size_t)4194304;        // [8, 16 MB)
    bf16_t* Vt = Qb + (size_t)4194304;        // [16, 24 MB)
    bf16_t* Xb = (bf16_t*)(ws + 25165824);    // [24, 32 MB)
    bf16_t* Wt = Xb + (size_t)4194304;        // [32, 33.5 MB)

    const size_t NEED_PRE = 35127296;         // through Wt
    const bool has_pre = ws_size >= NEED_PRE;

    if (has_pre) {
        hipLaunchKernelGGL(prep_kernel, dim3(2240), dim3(256), 0, stream,
                           x, Wq, Wk, Wv, Xb, Wt);
        hipLaunchKernelGGL(proj_bf16, dim3(64, 12), dim3(256), 0, stream,
                           Xb, Wt, Qb, Kb, Vt);
    } else {
        hipLaunchKernelGGL(proj_kernel, dim3(64, 8, 3), dim3(256), 0, stream,
                           x, Wq, Wk, Wv, Qb, Kb, Vt);
    }

    hipLaunchKernelGGL(attn_kernel, dim3(512), dim3(512), 0, stream,
                       Kb, Qb, Vt, out);
}